// Round 1
// 426.689 us; speedup vs baseline: 1.0758x; 1.0758x over previous
//
#include <hip/hip_runtime.h>

// Problem constants
#define BATCH 2048
#define KIN   64
#define KOUT  64
#define NPT   256                        // block FFT length
#define NF    129                        // half-spectrum bins
#define FSTRIDE (BATCH * KIN)            // 131072 floats per f-plane row
#define XPLANE ((size_t)NF * FSTRIDE)    // 16,908,288 floats per re/im plane
#define WPLANE (NF * KIN * KOUT)         // 528,384 floats
#define NFP 133                          // padded staging row stride (gcd(5,32)=1)

// wave-level LDS fence: wave64 lockstep + in-order DS pipe makes this a valid
// substitute for __syncthreads() on wave-private LDS regions.
#define WAVE_SYNC() __asm__ volatile("s_waitcnt lgkmcnt(0)" ::: "memory")

// LDS index pad for FFT buffers: spreads power-of-2 strides across banks.
__device__ __forceinline__ int PHI(int i) { return i + (i >> 5); }

// ---------------------------------------------------------------------------
// Hoisted twiddles: jm depends only on (stage, lane), so compute the three
// twiddle factors per stage ONCE per wave (24 VGPRs) instead of per FFT.
// Values are bit-identical to the previous per-iteration computation.
// ---------------------------------------------------------------------------
template<int SIGN>
__device__ __forceinline__ void make_twiddles(int lane,
                                              float (&cw)[4],  float (&sw)[4],
                                              float (&c2w)[4], float (&s2w)[4],
                                              float (&c3w)[4], float (&s3w)[4]) {
  const float C = SIGN * (6.28318530717958647692f / 256.f);
#pragma unroll
  for (int st = 0; st < 4; ++st) {
    const int m  = 1 << (2 * st);
    const int jm = lane & ~(m - 1);
    float s, c;
    __sincosf(C * (float)jm, &s, &c);
    cw[st] = c;  sw[st] = s;
    c2w[st] = c * c - s * s;           s2w[st] = 2.f * c * s;          // W(2jm)
    c3w[st] = c2w[st] * c - s2w[st] * s;
    s3w[st] = c2w[st] * s + s2w[st] * c;                              // W(3jm)
  }
}

// ---------------------------------------------------------------------------
// Radix-4 Stockham FFT, 256 points, one wave (64 lanes), wave-private LDS
// ping-pong buffers (264 float2 each, PHI-indexed). 4 stages, result in A.
// Twiddles are precomputed per lane (see make_twiddles).
// ---------------------------------------------------------------------------
template<int SIGN>
__device__ __forceinline__ void fft256_tw(float2* A, float2* B, int lane,
                                          const float (&cw)[4],  const float (&sw)[4],
                                          const float (&c2w)[4], const float (&s2w)[4],
                                          const float (&c3w)[4], const float (&s3w)[4]) {
  float2* src = A;
  float2* dst = B;
#pragma unroll
  for (int st = 0; st < 4; ++st) {
    const int m  = 1 << (2 * st);
    const int t  = lane;
    const int jm = t & ~(m - 1);
    float2 s0 = src[PHI(t)];
    float2 s1 = src[PHI(t + 64)];
    float2 s2 = src[PHI(t + 128)];
    float2 s3 = src[PHI(t + 192)];
    float apcx = s0.x + s2.x, apcy = s0.y + s2.y;
    float amcx = s0.x - s2.x, amcy = s0.y - s2.y;
    float bpdx = s1.x + s3.x, bpdy = s1.y + s3.y;
    float bmdx = s1.x - s3.x, bmdy = s1.y - s3.y;
    // sign*i*(bx+i by) = sign*(-by + i bx)
    float sbx = (SIGN < 0) ? bmdy : -bmdy;
    float sby = (SIGN < 0) ? -bmdx : bmdx;
    float t1x = amcx + sbx, t1y = amcy + sby;
    float t3x = amcx - sbx, t3y = amcy - sby;
    float t2x = apcx - bpdx, t2y = apcy - bpdy;
    const int base = t + 3 * jm;
    dst[PHI(base)]         = make_float2(apcx + bpdx, apcy + bpdy);
    dst[PHI(base + m)]     = make_float2(cw[st] * t1x - sw[st] * t1y,
                                         cw[st] * t1y + sw[st] * t1x);
    dst[PHI(base + 2 * m)] = make_float2(c2w[st] * t2x - s2w[st] * t2y,
                                         c2w[st] * t2y + s2w[st] * t2x);
    dst[PHI(base + 3 * m)] = make_float2(c3w[st] * t3x - s3w[st] * t3y,
                                         c3w[st] * t3y + s3w[st] * t3x);
    WAVE_SYNC();
    float2* tmp = src; src = dst; dst = tmp;
  }
}

// ---------------------------------------------------------------------------
// k0: tiled transpose W[i][j][f] -> Wtr/Wti[f][j*64+i], both sides coalesced.
// ---------------------------------------------------------------------------
__global__ __launch_bounds__(256) void k0_wtrans(const float* __restrict__ Wre,
                                                 const float* __restrict__ Wim,
                                                 float* __restrict__ Wtr,
                                                 float* __restrict__ Wti) {
  __shared__ float T[32][33];
  const int f0 = blockIdx.y * 32;       // 0,32,64,96,128
  const int d0 = blockIdx.x * 32;       // dest inner index d = j*64+i
  const int t  = threadIdx.x;
  const int a  = t & 31, g = t >> 5;
#pragma unroll
  for (int pl = 0; pl < 2; ++pl) {
    const float* src = pl ? Wim : Wre;
    float* dst = pl ? Wti : Wtr;
    if (pl) __syncthreads();
#pragma unroll
    for (int it = 0; it < 4; ++it) {
      int dl = g + it * 8;
      int d  = d0 + dl;
      int s  = (d & 63) * 64 + (d >> 6);   // source row i*64+j
      int f  = f0 + a;
      if (f < NF) T[dl][a] = src[(size_t)s * NF + f];
    }
    __syncthreads();
#pragma unroll
    for (int it = 0; it < 4; ++it) {
      int fl = g + it * 8;
      int f  = f0 + fl;
      if (f < NF) dst[(size_t)f * (KIN * KOUT) + d0 + a] = T[a][fl];
    }
  }
}

// ---------------------------------------------------------------------------
// k1: rfft of 32 (b,j) blocks per workgroup (one b, half the j's).
// PACKED-REAL: two real blocks per complex FFT (z = x1 + i*x2), unpacked via
// conjugate symmetry -> halves FFT count (16 complex FFTs per block).
// Fused LDS-staged transpose, coalesced writes to f-major planes Xtr/Xti.
// ---------------------------------------------------------------------------
__global__ __launch_bounds__(256) void k1_rfft(const float* __restrict__ x,
                                               float* __restrict__ Xtr,
                                               float* __restrict__ Xti) {
  __shared__ float2 fbuf[4][2][264];    // 16.9 KB
  __shared__ float Sr[32 * NFP];        // 17 KB
  __shared__ float Si[32 * NFP];        // 17 KB
  const int wave = threadIdx.x >> 6, lane = threadIdx.x & 63;
  const int b = blockIdx.x >> 1, h = blockIdx.x & 1;
  float2* A  = fbuf[wave][0];
  float2* Bp = fbuf[wave][1];

  float cw[4], sw[4], c2w[4], s2w[4], c3w[4], s3w[4];
  make_twiddles<-1>(lane, cw, sw, c2w, s2w, c3w, s3w);

#pragma unroll
  for (int u = 0; u < 4; ++u) {
    const int p   = u * 4 + wave;                 // packed-FFT index 0..15
    const int jt1 = 2 * p, jt2 = 2 * p + 1;       // staging rows 0..31
    const size_t idx1 = (size_t)b * 64 + h * 32 + jt1;
    float4 va = reinterpret_cast<const float4*>(x + idx1 * NPT)[lane];
    float4 vb = reinterpret_cast<const float4*>(x + (idx1 + 1) * NPT)[lane];
    A[PHI(4 * lane + 0)] = make_float2(va.x, vb.x);
    A[PHI(4 * lane + 1)] = make_float2(va.y, vb.y);
    A[PHI(4 * lane + 2)] = make_float2(va.z, vb.z);
    A[PHI(4 * lane + 3)] = make_float2(va.w, vb.w);
    WAVE_SYNC();
    fft256_tw<-1>(A, Bp, lane, cw, sw, c2w, s2w, c3w, s3w);
    // unpack: X1(f) = 0.5*(Z(f)+conj(Z(-f))), X2(f) = -0.5i*(Z(f)-conj(Z(-f)))
    float2 zf  = A[PHI(lane)];
    float2 zfm = A[PHI((256 - lane) & 255)];
    float2 zg  = A[PHI(lane + 64)];
    float2 zgm = A[PHI(192 - lane)];
    // f = lane
    Sr[jt1 * NFP + lane] = 0.5f * (zf.x + zfm.x);
    Si[jt1 * NFP + lane] = 0.5f * (zf.y - zfm.y);
    Sr[jt2 * NFP + lane] = 0.5f * (zf.y + zfm.y);
    Si[jt2 * NFP + lane] = 0.5f * (zfm.x - zf.x);
    // f = lane + 64
    Sr[jt1 * NFP + lane + 64] = 0.5f * (zg.x + zgm.x);
    Si[jt1 * NFP + lane + 64] = 0.5f * (zg.y - zgm.y);
    Sr[jt2 * NFP + lane + 64] = 0.5f * (zg.y + zgm.y);
    Si[jt2 * NFP + lane + 64] = 0.5f * (zgm.x - zg.x);
    if (lane == 0) {
      float2 zn = A[PHI(128)];                    // Nyquist: both spectra real
      Sr[jt1 * NFP + 128] = zn.x;  Si[jt1 * NFP + 128] = 0.f;
      Sr[jt2 * NFP + 128] = zn.y;  Si[jt2 * NFP + 128] = 0.f;
    }
    WAVE_SYNC();
  }
  __syncthreads();
  // cooperative coalesced write-out: 32 consecutive idx per f
  const int c = threadIdx.x & 31;
  const size_t baseidx = (size_t)b * 64 + h * 32 + c;
#pragma unroll
  for (int it = 0; it < 17; ++it) {
    int f = (threadIdx.x >> 5) + it * 8;
    if (f < NF) {
      Xtr[(size_t)f * FSTRIDE + baseidx] = Sr[c * NFP + f];
      Xti[(size_t)f * FSTRIDE + baseidx] = Si[c * NFP + f];
    }
  }
}

// ---------------------------------------------------------------------------
// k2: per-frequency complex GEMM  O[b][i] = sum_j X[b][j] * conj(W[i][j])
// f-major planes: all global access contiguous. In-place over X (tile fully
// staged to LDS before any write; blocks touch disjoint ranges).
// ---------------------------------------------------------------------------
__global__ __launch_bounds__(256) void k2_cgemm(float* __restrict__ Xr,
                                                float* __restrict__ Xi,
                                                const float* __restrict__ Wtr,
                                                const float* __restrict__ Wti) {
  __shared__ __align__(16) float Xlr[64 * 68];
  __shared__ __align__(16) float Xli[64 * 68];
  __shared__ __align__(16) float Wlr[64 * 68];
  __shared__ __align__(16) float Wli[64 * 68];

  const int f  = blockIdx.y;
  const int b0 = blockIdx.x * 64;
  const int t  = threadIdx.x;
  const size_t xbase = (size_t)f * FSTRIDE + (size_t)b0 * 64;
  const float* wpr = Wtr + (size_t)f * (KIN * KOUT);
  const float* wpi = Wti + (size_t)f * (KIN * KOUT);

  // W tile: [j][i], vector load + vector store (already in [j][i] layout)
#pragma unroll
  for (int it = 0; it < 4; ++it) {
    int n4 = (it * 256 + t) * 4;
    int j = n4 >> 6, i0 = n4 & 63;
    float4 wr = *reinterpret_cast<const float4*>(wpr + n4);
    float4 wi = *reinterpret_cast<const float4*>(wpi + n4);
    *reinterpret_cast<float4*>(&Wlr[j * 68 + i0]) = wr;
    *reinterpret_cast<float4*>(&Wli[j * 68 + i0]) = wi;
  }
  // X tile: vector load rows, transposed scalar stores -> [j][r]
#pragma unroll
  for (int it = 0; it < 4; ++it) {
    int n4 = (it * 256 + t) * 4;
    int r = n4 >> 6, j0 = n4 & 63;
    float4 xr = *reinterpret_cast<const float4*>(Xr + xbase + n4);
    float4 xi = *reinterpret_cast<const float4*>(Xi + xbase + n4);
    Xlr[(j0 + 0) * 68 + r] = xr.x; Xlr[(j0 + 1) * 68 + r] = xr.y;
    Xlr[(j0 + 2) * 68 + r] = xr.z; Xlr[(j0 + 3) * 68 + r] = xr.w;
    Xli[(j0 + 0) * 68 + r] = xi.x; Xli[(j0 + 1) * 68 + r] = xi.y;
    Xli[(j0 + 2) * 68 + r] = xi.z; Xli[(j0 + 3) * 68 + r] = xi.w;
  }
  __syncthreads();

  const int tx = t & 15, ty = t >> 4;
  const int i0 = tx * 4, r0 = ty * 4;
  float aR[4][4] = {};
  float aI[4][4] = {};

#pragma unroll 4
  for (int j = 0; j < 64; ++j) {
    float4 xr = *reinterpret_cast<const float4*>(&Xlr[j * 68 + r0]);
    float4 xi = *reinterpret_cast<const float4*>(&Xli[j * 68 + r0]);
    float4 wr = *reinterpret_cast<const float4*>(&Wlr[j * 68 + i0]);
    float4 wi = *reinterpret_cast<const float4*>(&Wli[j * 68 + i0]);
    float xra[4] = {xr.x, xr.y, xr.z, xr.w};
    float xia[4] = {xi.x, xi.y, xi.z, xi.w};
    float wra[4] = {wr.x, wr.y, wr.z, wr.w};
    float wia[4] = {wi.x, wi.y, wi.z, wi.w};
#pragma unroll
    for (int a = 0; a < 4; ++a)
#pragma unroll
      for (int c = 0; c < 4; ++c) {
        // X * conj(W): re += xr*wr + xi*wi ; im += xi*wr - xr*wi
        aR[a][c] += xra[a] * wra[c] + xia[a] * wia[c];
        aI[a][c] += xia[a] * wra[c] - xra[a] * wia[c];
      }
  }

#pragma unroll
  for (int a = 0; a < 4; ++a) {
    size_t g = xbase + (size_t)(r0 + a) * 64 + i0;
    *reinterpret_cast<float4*>(&Xr[g]) = make_float4(aR[a][0], aR[a][1], aR[a][2], aR[a][3]);
    *reinterpret_cast<float4*>(&Xi[g]) = make_float4(aI[a][0], aI[a][1], aI[a][2], aI[a][3]);
  }
}

// ---------------------------------------------------------------------------
// k3: coalesced gather from f-major O planes into LDS staging, PACKED inverse
// FFT: Z(f) = O1(f) + i*O2(f) with conjugate-symmetric extension, one inverse
// complex FFT yields TWO real output blocks (Re -> block1, Im -> block2).
// ---------------------------------------------------------------------------
__global__ __launch_bounds__(256) void k3_irfft(const float* __restrict__ Or,
                                                const float* __restrict__ Oi,
                                                float* __restrict__ out) {
  __shared__ float2 fbuf[4][2][264];
  __shared__ float Sr[32 * NFP];
  __shared__ float Si[32 * NFP];
  const int wave = threadIdx.x >> 6, lane = threadIdx.x & 63;
  const int b = blockIdx.x >> 1, h = blockIdx.x & 1;
  const int c = threadIdx.x & 31;
  const size_t baseidx = (size_t)b * 64 + h * 32 + c;
#pragma unroll
  for (int it = 0; it < 17; ++it) {
    int f = (threadIdx.x >> 5) + it * 8;
    if (f < NF) {
      Sr[c * NFP + f] = Or[(size_t)f * FSTRIDE + baseidx];
      Si[c * NFP + f] = Oi[(size_t)f * FSTRIDE + baseidx];
    }
  }
  __syncthreads();
  float2* A  = fbuf[wave][0];
  float2* Bp = fbuf[wave][1];

  float cw[4], sw[4], c2w[4], s2w[4], c3w[4], s3w[4];
  make_twiddles<1>(lane, cw, sw, c2w, s2w, c3w, s3w);

#pragma unroll
  for (int u = 0; u < 4; ++u) {
    const int p  = u * 4 + wave;                  // packed pair index 0..15
    const int p1 = 2 * p, p2 = 2 * p + 1;         // staging rows / out blocks
    // gather both rows at f = lane and f = lane+64
    float a1r = Sr[p1 * NFP + lane],      a1i = Si[p1 * NFP + lane];
    float b1r = Sr[p1 * NFP + lane + 64], b1i = Si[p1 * NFP + lane + 64];
    float a2r = Sr[p2 * NFP + lane],      a2i = Si[p2 * NFP + lane];
    float b2r = Sr[p2 * NFP + lane + 64], b2i = Si[p2 * NFP + lane + 64];
    // Z(f) = O1(f) + i*O2(f);  Z(256-f) = conj(O1(f)) + i*conj(O2(f))
    A[PHI(lane)]      = make_float2(a1r - a2i, a1i + a2r);          // f = 0..63
    A[PHI(lane + 64)] = make_float2(b1r - b2i, b1i + b2r);          // f = 64..127
    if (lane) A[PHI(256 - lane)] = make_float2(a1r + a2i, a2r - a1i); // 193..255
    A[PHI(192 - lane)] = make_float2(b1r + b2i, b2r - b1i);         // 129..192
    if (lane == 0) {
      float n1r = Sr[p1 * NFP + 128], n1i = Si[p1 * NFP + 128];
      float n2r = Sr[p2 * NFP + 128], n2i = Si[p2 * NFP + 128];
      A[PHI(128)] = make_float2(n1r - n2i, n1i + n2r);
    }
    WAVE_SYNC();
    fft256_tw<1>(A, Bp, lane, cw, sw, c2w, s2w, c3w, s3w);
    const float s = 1.0f / 256.f;
    float4 o1, o2;
    float2 e0 = A[PHI(4 * lane + 0)];
    float2 e1 = A[PHI(4 * lane + 1)];
    float2 e2 = A[PHI(4 * lane + 2)];
    float2 e3 = A[PHI(4 * lane + 3)];
    o1.x = e0.x * s; o1.y = e1.x * s; o1.z = e2.x * s; o1.w = e3.x * s;
    o2.x = e0.y * s; o2.y = e1.y * s; o2.z = e2.y * s; o2.w = e3.y * s;
    const size_t idx1 = (size_t)b * 64 + h * 32 + p1;
    reinterpret_cast<float4*>(out + idx1 * NPT)[lane] = o1;
    reinterpret_cast<float4*>(out + (idx1 + 1) * NPT)[lane] = o2;
    WAVE_SYNC();
  }
}

// ---------------------------------------------------------------------------
extern "C" void kernel_launch(void* const* d_in, const int* in_sizes, int n_in,
                              void* d_out, int out_size, void* d_ws, size_t ws_size,
                              hipStream_t stream) {
  const float* x   = (const float*)d_in[0];
  const float* Wre = (const float*)d_in[1];
  const float* Wim = (const float*)d_in[2];
  float* out = (float*)d_out;
  float* ws  = (float*)d_ws;

  float* Xr  = ws;                      // f-major plane [f][b*64+j]
  float* Xi  = ws + XPLANE;
  float* Wtr = ws + 2 * XPLANE;         // [f][j*64+i]
  float* Wti = Wtr + WPLANE;
  // ws use: (2*XPLANE + 2*WPLANE)*4 B ~= 139.5 MB

  hipLaunchKernelGGL(k0_wtrans, dim3(128, 5), dim3(256), 0, stream,
                     Wre, Wim, Wtr, Wti);
  hipLaunchKernelGGL(k1_rfft, dim3(BATCH * 2), dim3(256), 0, stream,
                     x, Xr, Xi);
  hipLaunchKernelGGL(k2_cgemm, dim3(BATCH / 64, NF), dim3(256), 0, stream,
                     Xr, Xi, Wtr, Wti);
  hipLaunchKernelGGL(k3_irfft, dim3(BATCH * 2), dim3(256), 0, stream,
                     Xr, Xi, out);
}